// Round 11
// baseline (127.616 us; speedup 1.0000x reference)
//
#include <hip/hip_runtime.h>

typedef float  f32x4  __attribute__((ext_vector_type(4)));
typedef short  short8 __attribute__((ext_vector_type(8)));
typedef unsigned short ushort_t;
typedef ushort_t us4   __attribute__((ext_vector_type(4)));

#define NCOARSE 1024
#define NFINE   4096

// opaque global load: LLVM cannot sink, rematerialize, or spill-refill this
// from source; the value is pinned in 4 VGPRs from issue to last use.
#define GLD(dst, ptr) \
  asm volatile("global_load_dwordx4 %0, %1, off" : "=&v"(dst) : "v"(ptr))

__device__ __forceinline__ ushort_t f2bf(float f){
  union { float f; unsigned u; } a; a.f = f;
  unsigned u = a.u;
  return (ushort_t)((u + 0x7fffu + ((u >> 16) & 1u)) >> 16);
}

__device__ __forceinline__ f32x4 splat4(float v){ f32x4 t = {v, v, v, v}; return t; }

// ---- pack fp32 row-major W[K][256] into bf16, MFMA-B-fragment order:
// Wp[(((kc*16+nb)*64 + lane)*8 + j] = W[kc*32 + (lane>>4)*8 + j][nb*16 + (lane&15)]
__global__ void prep_w(const float* __restrict__ W, ushort_t* __restrict__ Wp, int nelem){
  int e = blockIdx.x * 256 + threadIdx.x;
  if (e >= nelem) return;
  int j    = e & 7;
  int lane = (e >> 3) & 63;
  int g    = e >> 9;        // kc*16 + nb
  int nb   = g & 15;
  int kc   = g >> 4;
  int k = kc * 32 + (lane >> 4) * 8 + j;
  int n = nb * 16 + (lane & 15);
  Wp[e] = f2bf(W[k * 256 + n]);
}

// ---- kNN, reference fp32 arithmetic EXACTLY (expansion form, no fma).
// 2 queries per thread: each cand LDS read feeds 2 distance evals.
__global__ __launch_bounds__(256) void knn_kernel(const float* __restrict__ pos,
                           const float* __restrict__ pos_skip,
                           int* __restrict__ knn_i, float* __restrict__ knn_w){
  __shared__ f32x4 cand[8][129];            // stride 129 -> chunk k on banks 4k..4k+3
  const int tid = threadIdx.x;
  const int b   = blockIdx.x >> 6;          // 64 blocks per cloud (4096/64)
  const int mA  = blockIdx.x * 64 + (tid >> 3);
  const int mB  = mA + 32;
  const int chunk = tid & 7;

  const float* p = pos + (size_t)b * NCOARSE * 3;
  for (int c = tid; c < NCOARSE; c += 256){
    float x = p[3*c], y = p[3*c+1], z = p[3*c+2];
    float sc = __fadd_rn(__fadd_rn(__fmul_rn(x,x), __fmul_rn(y,y)), __fmul_rn(z,z));
    f32x4 v = { x, y, z, sc };
    cand[c >> 7][c & 127] = v;
  }
  __syncthreads();

  const float* qA = pos_skip + (size_t)mA * 3;
  const float* qB = pos_skip + (size_t)mB * 3;
  float ax = qA[0], ay = qA[1], az = qA[2];
  float bx = qB[0], by = qB[1], bz = qB[2];
  float sfA = __fadd_rn(__fadd_rn(__fmul_rn(ax,ax), __fmul_rn(ay,ay)), __fmul_rn(az,az));
  float sfB = __fadd_rn(__fadd_rn(__fmul_rn(bx,bx), __fmul_rn(by,by)), __fmul_rn(bz,bz));

  float dA0 = 1e30f, dA1 = 1e30f, dA2 = 1e30f;
  int   iA0 = 0,     iA1 = 0,     iA2 = 0;
  float dB0 = 1e30f, dB1 = 1e30f, dB2 = 1e30f;
  int   iB0 = 0,     iB1 = 0,     iB2 = 0;
  const int gbase = chunk * 128;
  #pragma unroll 2
  for (int i = 0; i < 128; ++i){
    f32x4 v = cand[chunk][i];
    int gi = gbase + i;
    float dotA = __fadd_rn(__fadd_rn(__fmul_rn(ax, v.x), __fmul_rn(ay, v.y)),
                           __fmul_rn(az, v.z));
    float dA = fmaxf(__fsub_rn(__fadd_rn(sfA, v.w), __fmul_rn(2.0f, dotA)), 0.0f);
    if (dA < dA2){
      if (dA < dA1){
        dA2 = dA1; iA2 = iA1;
        if (dA < dA0){ dA1 = dA0; iA1 = iA0; dA0 = dA; iA0 = gi; }
        else         { dA1 = dA;  iA1 = gi; }
      } else { dA2 = dA; iA2 = gi; }
    }
    float dotB = __fadd_rn(__fadd_rn(__fmul_rn(bx, v.x), __fmul_rn(by, v.y)),
                           __fmul_rn(bz, v.z));
    float dB = fmaxf(__fsub_rn(__fadd_rn(sfB, v.w), __fmul_rn(2.0f, dotB)), 0.0f);
    if (dB < dB2){
      if (dB < dB1){
        dB2 = dB1; iB2 = iB1;
        if (dB < dB0){ dB1 = dB0; iB1 = iB0; dB0 = dB; iB0 = gi; }
        else         { dB1 = dB;  iB1 = gi; }
      } else { dB2 = dB; iB2 = gi; }
    }
  }

  #pragma unroll
  for (int mlev = 1; mlev <= 4; mlev <<= 1){
    float e0 = __shfl_xor(dA0, mlev), e1 = __shfl_xor(dA1, mlev), e2 = __shfl_xor(dA2, mlev);
    int   j0 = __shfl_xor(iA0, mlev), j1 = __shfl_xor(iA1, mlev), j2 = __shfl_xor(iA2, mlev);
    #pragma unroll
    for (int s = 0; s < 3; ++s){
      float e = (s == 0) ? e0 : (s == 1) ? e1 : e2;
      int   j = (s == 0) ? j0 : (s == 1) ? j1 : j2;
      bool l2 = (e < dA2) || (e == dA2 && j < iA2);
      if (l2){
        bool l1 = (e < dA1) || (e == dA1 && j < iA1);
        if (l1){
          dA2 = dA1; iA2 = iA1;
          bool l0 = (e < dA0) || (e == dA0 && j < iA0);
          if (l0){ dA1 = dA0; iA1 = iA0; dA0 = e; iA0 = j; }
          else   { dA1 = e;  iA1 = j; }
        } else { dA2 = e; iA2 = j; }
      }
    }
    float f0 = __shfl_xor(dB0, mlev), f1 = __shfl_xor(dB1, mlev), f2 = __shfl_xor(dB2, mlev);
    int   k0 = __shfl_xor(iB0, mlev), k1 = __shfl_xor(iB1, mlev), k2 = __shfl_xor(iB2, mlev);
    #pragma unroll
    for (int s = 0; s < 3; ++s){
      float e = (s == 0) ? f0 : (s == 1) ? f1 : f2;
      int   j = (s == 0) ? k0 : (s == 1) ? k1 : k2;
      bool l2 = (e < dB2) || (e == dB2 && j < iB2);
      if (l2){
        bool l1 = (e < dB1) || (e == dB1 && j < iB1);
        if (l1){
          dB2 = dB1; iB2 = iB1;
          bool l0 = (e < dB0) || (e == dB0 && j < iB0);
          if (l0){ dB1 = dB0; iB1 = iB0; dB0 = e; iB0 = j; }
          else   { dB1 = e;  iB1 = j; }
        } else { dB2 = e; iB2 = j; }
      }
    }
  }

  if (chunk == 0){
    {
      float w0 = 1.0f / fmaxf(dA0, 1e-16f);
      float w1 = 1.0f / fmaxf(dA1, 1e-16f);
      float w2 = 1.0f / fmaxf(dA2, 1e-16f);
      float ws = __fadd_rn(__fadd_rn(w0, w1), w2);
      knn_i[3*mA]   = b * NCOARSE + iA0;
      knn_i[3*mA+1] = b * NCOARSE + iA1;
      knn_i[3*mA+2] = b * NCOARSE + iA2;
      knn_w[3*mA]   = w0 / ws;
      knn_w[3*mA+1] = w1 / ws;
      knn_w[3*mA+2] = w2 / ws;
    }
    {
      float w0 = 1.0f / fmaxf(dB0, 1e-16f);
      float w1 = 1.0f / fmaxf(dB1, 1e-16f);
      float w2 = 1.0f / fmaxf(dB2, 1e-16f);
      float ws = __fadd_rn(__fadd_rn(w0, w1), w2);
      knn_i[3*mB]   = b * NCOARSE + iB0;
      knn_i[3*mB+1] = b * NCOARSE + iB1;
      knn_i[3*mB+2] = b * NCOARSE + iB2;
      knn_w[3*mB]   = w0 / ws;
      knn_w[3*mB+1] = w1 / ws;
      knn_w[3*mB+2] = w2 / ws;
    }
  }
}

// ---- persistent fused FP: 256 blocks x 512 threads; block owns 256 rows
// (8 tiles x 32). Wave wq owns output cols [wq*32, wq*32+32).
// W1+W2 wave-slices (160 VGPRs) live in registers for the whole kernel via
// opaque asm loads. K-loops touch only LDS + registers.
__global__ __launch_bounds__(512, 2)
void fused_fp(const float* __restrict__ x, const float* __restrict__ x_skip,
              const int* __restrict__ knn_i, const float* __restrict__ knn_w,
              const ushort_t* __restrict__ W1p, const float* __restrict__ b1,
              const ushort_t* __restrict__ W2p, const float* __restrict__ b2,
              float* __restrict__ out){
  __shared__ ushort_t h1[2][32 * 384];   // 2 x 24KB, swizzled rows (stride 768B)
  __shared__ ushort_t h2[32 * 256];      // 16KB, swizzled rows (stride 512B)
  const int tid  = threadIdx.x;
  const int lb   = ((blockIdx.x & 7) << 5) + (blockIdx.x >> 3);  // bijective: 256 = 8*32
  const int wq   = tid >> 6;
  const int lane = tid & 63;
  const int lhi  = lane >> 4;
  const int llo  = lane & 15;
  const int r    = tid >> 4;   // gather: 16 threads per row
  const int sub  = tid & 15;

  // ---- W slices -> registers, once (opaque to the optimizer)
  short8 w1f[12][2];
  short8 w2f[8][2];
  #pragma unroll
  for (int kk = 0; kk < 12; ++kk)
    #pragma unroll
    for (int nb = 0; nb < 2; ++nb){
      const ushort_t* p = W1p + ((size_t)((kk * 16 + wq * 2 + nb) * 64 + lane)) * 8;
      GLD(w1f[kk][nb], p);
    }
  #pragma unroll
  for (int kk = 0; kk < 8; ++kk)
    #pragma unroll
    for (int nb = 0; nb < 2; ++nb){
      const ushort_t* p = W2p + ((size_t)((kk * 16 + wq * 2 + nb) * 64 + lane)) * 8;
      GLD(w2f[kk][nb], p);
    }

  const float bb10 = b1[wq * 32 + llo];
  const float bb11 = b1[wq * 32 + 16 + llo];
  const float bb20 = b2[wq * 32 + llo];
  const float bb21 = b2[wq * 32 + 16 + llo];

  auto gather_tile = [&](char* h1b, int row0){
    const int m = row0 + r;
    int i0 = knn_i[3*m], i1 = knn_i[3*m+1], i2 = knn_i[3*m+2];
    float w0 = knn_w[3*m], w1 = knn_w[3*m+1], w2 = knn_w[3*m+2];
    const f32x4* x0 = (const f32x4*)(x + (size_t)i0 * 256);
    const f32x4* x1 = (const f32x4*)(x + (size_t)i1 * 256);
    const f32x4* x2 = (const f32x4*)(x + (size_t)i2 * 256);
    #pragma unroll
    for (int it = 0; it < 4; ++it){
      int c4 = it * 16 + sub;
      f32x4 v = x0[c4] * w0 + x1[c4] * w1 + x2[c4] * w2;
      int byte = (r * 768 + c4 * 8) ^ ((r & 7) << 4);
      us4 pk = { f2bf(v.x), f2bf(v.y), f2bf(v.z), f2bf(v.w) };
      *(us4*)(h1b + byte) = pk;
    }
    const f32x4* xs = (const f32x4*)(x_skip + (size_t)m * 128);
    #pragma unroll
    for (int it = 0; it < 2; ++it){
      int c4 = it * 16 + sub;
      f32x4 v = xs[c4];
      int byte = (r * 768 + 512 + c4 * 8) ^ ((r & 7) << 4);
      us4 pk = { f2bf(v.x), f2bf(v.y), f2bf(v.z), f2bf(v.w) };
      *(us4*)(h1b + byte) = pk;
    }
  };

  // prologue: tile 0 gather; barrier also drains the W asm loads (vmcnt 0)
  gather_tile((char*)h1[0], lb * 256);
  asm volatile("s_waitcnt vmcnt(0)");
  __builtin_amdgcn_sched_barrier(0);
  __syncthreads();

  for (int t = 0; t < 8; ++t){
    const int rowbase = lb * 256 + t * 32;
    char* h1b = (char*)h1[t & 1];
    char* h2b = (char*)h2;

    // ---- GEMM1: 12 K-steps, A from LDS, B from registers
    f32x4 acc1[2][2];
    acc1[0][0] = splat4(bb10); acc1[1][0] = splat4(bb10);
    acc1[0][1] = splat4(bb11); acc1[1][1] = splat4(bb11);
    #pragma unroll
    for (int kk = 0; kk < 12; ++kk){
      short8 af[2];
      #pragma unroll
      for (int mb = 0; mb < 2; ++mb){
        int rr = mb * 16 + llo;
        int byte = (rr * 768 + kk * 64 + lhi * 16) ^ ((rr & 7) << 4);
        af[mb] = *(const short8*)(h1b + byte);
      }
      #pragma unroll
      for (int mb = 0; mb < 2; ++mb)
        #pragma unroll
        for (int nb = 0; nb < 2; ++nb)
          acc1[mb][nb] = __builtin_amdgcn_mfma_f32_16x16x32_bf16(
              af[mb], w1f[kk][nb], acc1[mb][nb], 0, 0, 0);
    }

    // ---- relu -> bf16 -> h2 (swizzled)
    #pragma unroll
    for (int mb = 0; mb < 2; ++mb)
      #pragma unroll
      for (int nb = 0; nb < 2; ++nb)
        #pragma unroll
        for (int rg = 0; rg < 4; ++rg){
          int rr  = mb * 16 + lhi * 4 + rg;
          int col = wq * 32 + nb * 16 + llo;
          int byte = (rr * 512 + col * 2) ^ ((rr & 7) << 4);
          *(ushort_t*)(h2b + byte) = f2bf(fmaxf(acc1[mb][nb][rg], 0.0f));
        }
    __syncthreads();                       // h2 ready; h1 reads of this tile done

    // ---- gather tile t+1 into the other h1 buffer (overlaps GEMM2)
    if (t < 7) gather_tile((char*)h1[(t + 1) & 1], rowbase + 32);

    // ---- GEMM2: 8 K-steps, A from LDS h2, B from registers
    f32x4 acc2[2][2];
    acc2[0][0] = splat4(bb20); acc2[1][0] = splat4(bb20);
    acc2[0][1] = splat4(bb21); acc2[1][1] = splat4(bb21);
    #pragma unroll
    for (int kk = 0; kk < 8; ++kk){
      short8 af[2];
      #pragma unroll
      for (int mb = 0; mb < 2; ++mb){
        int rr = mb * 16 + llo;
        int byte = (rr * 512 + kk * 64 + lhi * 16) ^ ((rr & 7) << 4);
        af[mb] = *(const short8*)(h2b + byte);
      }
      #pragma unroll
      for (int mb = 0; mb < 2; ++mb)
        #pragma unroll
        for (int nb = 0; nb < 2; ++nb)
          acc2[mb][nb] = __builtin_amdgcn_mfma_f32_16x16x32_bf16(
              af[mb], w2f[kk][nb], acc2[mb][nb], 0, 0, 0);
    }

    // ---- relu -> fp32 out
    #pragma unroll
    for (int mb = 0; mb < 2; ++mb)
      #pragma unroll
      for (int nb = 0; nb < 2; ++nb)
        #pragma unroll
        for (int rg = 0; rg < 4; ++rg){
          int row = rowbase + mb * 16 + lhi * 4 + rg;
          int col = wq * 32 + nb * 16 + llo;
          out[(size_t)row * 256 + col] = fmaxf(acc2[mb][nb][rg], 0.0f);
        }

    if (t < 7) __syncthreads();            // h2 free + h1[(t+1)&1] visible
  }
}

extern "C" void kernel_launch(void* const* d_in, const int* in_sizes, int n_in,
                              void* d_out, int out_size, void* d_ws, size_t ws_size,
                              hipStream_t stream){
  (void)in_sizes; (void)n_in; (void)out_size; (void)ws_size;
  const float* x        = (const float*)d_in[0];
  const float* pos      = (const float*)d_in[1];
  const float* x_skip   = (const float*)d_in[3];
  const float* pos_skip = (const float*)d_in[4];
  const float* W1 = (const float*)d_in[6];
  const float* b1 = (const float*)d_in[7];
  const float* W2 = (const float*)d_in[8];
  const float* b2 = (const float*)d_in[9];
  float* out = (float*)d_out;
  char* ws = (char*)d_ws;
  ushort_t* W1p = (ushort_t*)(ws);                 // 196608 B
  ushort_t* W2p = (ushort_t*)(ws + 196608);        // 131072 B
  int*      ki  = (int*)(ws + 327680);             // 786432 B
  float*    kw  = (float*)(ws + 1114112);          // 786432 B

  hipLaunchKernelGGL(prep_w, dim3(384), dim3(256), 0, stream, W1, W1p, 98304);
  hipLaunchKernelGGL(prep_w, dim3(256), dim3(256), 0, stream, W2, W2p, 65536);
  hipLaunchKernelGGL(knn_kernel, dim3(1024), dim3(256), 0, stream, pos, pos_skip, ki, kw);
  hipLaunchKernelGGL(fused_fp, dim3(256), dim3(512), 0, stream,
                     x, x_skip, ki, kw, W1p, b1, W2p, b2, out);
}